// Round 13
// baseline (224.343 us; speedup 1.0000x reference)
//
#include <hip/hip_runtime.h>

#define TLEN 4096
#define DIM 1024
#define NHEAD 16
#define HDIM 64
#define QKV_COLS (3 * DIM)
// 0.125 * log2(e): attention scores computed in exp2 domain (v_exp_f32 is 2^x)
#define QSCALE 0.1803368801111244f
#define NCHUNK 4
#define SCHUNK (TLEN / NCHUNK)
#define TB 256        // t rows per attn block (wave owns 64 t = 4 strips of 16)
#define NIT (SCHUNK / 64)

typedef __attribute__((ext_vector_type(8))) short short8;   // 8 bf16 = 4 VGPR (MFMA A/B frag)
typedef __attribute__((ext_vector_type(4))) float f32x4;    // MFMA C/D frag

struct alignas(8) s4 { short v[4]; };

__device__ float g_Lsum[NHEAD];

__device__ __forceinline__ unsigned bf16_rtne_bits(float x) {
    unsigned u = __float_as_uint(x);
    return (u + 0x7fffu + ((u >> 16) & 1u)) >> 16;
}

// async global->LDS 16B copy (global_load_lds_dwordx4). LDS dest must be
// wave-uniform base + lane*16 at the callsite (our staging layouts are).
__device__ __forceinline__ void cp16(const short* g, short* l) {
    __builtin_amdgcn_global_load_lds(
        (const __attribute__((address_space(1))) unsigned int*)g,
        (__attribute__((address_space(3))) unsigned int*)l,
        16, 0, 0);
}

__device__ __forceinline__ short8 mk8(unsigned a, unsigned b, unsigned c, unsigned d) {
    union { unsigned u[4]; short8 s; } t;
    t.u[0] = a; t.u[1] = b; t.u[2] = c; t.u[3] = d;
    return t.s;
}

// Fused fp32->bf16 conversion of x (4M elems) and W_in (3M elems); one launch.
__global__ __launch_bounds__(256) void conv_in(
    const float* __restrict__ x, const float* __restrict__ W_in,
    short* __restrict__ xb, short* __restrict__ wib)
{
    const int XN4 = TLEN * DIM / 4;        // 1048576
    const int WN4 = QKV_COLS * DIM / 4;    // 786432
    int i = blockIdx.x * 256 + threadIdx.x;
    const float* src; short* dst; int j;
    if (i < XN4)            { src = x;    dst = xb;  j = i; }
    else if (i < XN4 + WN4) { src = W_in; dst = wib; j = i - XN4; }
    else return;
    float4 v = ((const float4*)src)[j];
    s4 o;
    o.v[0] = (short)bf16_rtne_bits(v.x);
    o.v[1] = (short)bf16_rtne_bits(v.y);
    o.v[2] = (short)bf16_rtne_bits(v.z);
    o.v[3] = (short)bf16_rtne_bits(v.w);
    ((s4*)dst)[j] = o;
}

// W_out [1024,1024] -> bf16 with per-head 1/L folded in (k-group = k/64).
// Runs AFTER combine4 (its output region overlays part chunk c1).
__global__ __launch_bounds__(256) void conv_wout(
    const float* __restrict__ src, short* __restrict__ dst)
{
    int i = blockIdx.x * 256 + threadIdx.x;   // over 1024*1024/4
    float s = 1.0f / g_Lsum[(i & 255) >> 4];  // k = (i&255)*4; head = k>>6
    float4 v = ((const float4*)src)[i];
    s4 o;
    o.v[0] = (short)bf16_rtne_bits(v.x * s);
    o.v[1] = (short)bf16_rtne_bits(v.y * s);
    o.v[2] = (short)bf16_rtne_bits(v.z * s);
    o.v[3] = (short)bf16_rtne_bits(v.w * s);
    ((s4*)dst)[i] = o;
}

// attnb = bf16(p0+p1+p2+p3); n4 = elements/4. dst aliases p0 (elementwise,
// same-index read->write: safe).
__global__ __launch_bounds__(256) void combine4(
    const short* __restrict__ p0, const short* __restrict__ p1,
    const short* __restrict__ p2, const short* __restrict__ p3,
    short* __restrict__ dst, int n4)
{
    int i = blockIdx.x * 256 + threadIdx.x;
    if (i < n4) {
        s4 a = ((const s4*)p0)[i];
        s4 b = ((const s4*)p1)[i];
        s4 c = ((const s4*)p2)[i];
        s4 d = ((const s4*)p3)[i];
        s4 o;
#pragma unroll
        for (int m = 0; m < 4; ++m) {
            float fa = __uint_as_float(((unsigned)(unsigned short)a.v[m]) << 16);
            float fb = __uint_as_float(((unsigned)(unsigned short)b.v[m]) << 16);
            float fc = __uint_as_float(((unsigned)(unsigned short)c.v[m]) << 16);
            float fd = __uint_as_float(((unsigned)(unsigned short)d.v[m]) << 16);
            o.v[m] = (short)bf16_rtne_bits((fa + fb) + (fc + fd));
        }
        ((s4*)dst)[i] = o;
    }
}

// C = A @ B^T, bf16 MFMA. BMx128 tile (BM=128 or 64), 4 waves, BK=32.
// Staging via async global_load_lds width=16. XCD-aware block swizzle
// (bijective: both grids divisible by 8).
// QKV_MODE: bf16 out; Q cols (n<DIM) scaled by QSCALE; V cols (n>=2*DIM)
//   written TRANSPOSED to Vout[d_global][t] as packed uint2. Also zeroes
//   g_Lsum from one designated block (attn runs strictly after in stream).
// else: fp32 out to Cout.
template <bool QKV_MODE, int BM>
__global__ __launch_bounds__(256) void gemm_bt(
    const short* __restrict__ A, const short* __restrict__ B,
    void* __restrict__ Cout, short* __restrict__ Vout, int M, int N, int K)
{
    constexpr int MI = BM / 32;   // i-strips per wave (wave covers BM/2 rows)
    __shared__ __align__(16) short As[BM][32];
    __shared__ __align__(16) short Bs[128][32];
    const int tid  = threadIdx.x;
    const int wv   = tid >> 6, lane = tid & 63;
    const int fr   = lane & 15, quad = lane >> 4;
    const int wm   = (wv >> 1) * (BM / 2), wn = (wv & 1) * 64;

    // XCD-aware swizzle of the flattened block id (nwg % 8 == 0 for both uses)
    const int nwg = gridDim.x * gridDim.y;
    const int bid = blockIdx.y * gridDim.x + blockIdx.x;
    const int swz = (bid & 7) * (nwg >> 3) + (bid >> 3);
    const int bx = swz % gridDim.x, by = swz / gridDim.x;
    const int m0 = bx * BM, n0 = by * 128;

    if (QKV_MODE && bx == 0 && by == 0 && tid < NHEAD)
        g_Lsum[tid] = 0.0f;

    f32x4 acc[MI][4] = {};

    for (int k0 = 0; k0 < K; k0 += 32) {
        __syncthreads();
#pragma unroll
        for (int c = tid; c < 512; c += 256) {
            int row = c >> 2, col = (c & 3) * 8;
            if (BM == 128 || c < BM * 4)
                cp16(A + (size_t)(m0 + row) * K + k0 + col, &As[row][col]);
            cp16(B + (size_t)(n0 + row) * K + k0 + col, &Bs[row][col]);
        }
        __syncthreads();   // drains vmcnt (async LDS stores) before reads

        short8 af[MI], bfr[4];
#pragma unroll
        for (int i = 0; i < MI; ++i)
            af[i]  = *(const short8*)&As[wm + i * 16 + fr][quad * 8];
#pragma unroll
        for (int j = 0; j < 4; ++j)
            bfr[j] = *(const short8*)&Bs[wn + j * 16 + fr][quad * 8];
#pragma unroll
        for (int i = 0; i < MI; ++i)
#pragma unroll
            for (int j = 0; j < 4; ++j)
                acc[i][j] = __builtin_amdgcn_mfma_f32_16x16x32_bf16(af[i], bfr[j], acc[i][j], 0, 0, 0);
    }

    if (QKV_MODE && n0 >= 2 * DIM) {
        // V tile: write V^T[d_global][t], packed 4 consecutive t per lane
#pragma unroll
        for (int i = 0; i < MI; ++i)
#pragma unroll
            for (int j = 0; j < 4; ++j) {
                int n = n0 - 2 * DIM + wn + j * 16 + fr;        // d_global
                int m = m0 + wm + i * 16 + quad * 4;            // t base
                unsigned u0 = bf16_rtne_bits(acc[i][j][0]);
                unsigned u1 = bf16_rtne_bits(acc[i][j][1]);
                unsigned u2 = bf16_rtne_bits(acc[i][j][2]);
                unsigned u3 = bf16_rtne_bits(acc[i][j][3]);
                uint2 pk;
                pk.x = u0 | (u1 << 16);
                pk.y = u2 | (u3 << 16);
                *(uint2*)(Vout + (size_t)n * TLEN + m) = pk;
            }
    } else if (QKV_MODE) {
        const float sc = (n0 < DIM) ? QSCALE : 1.0f;
#pragma unroll
        for (int i = 0; i < MI; ++i)
#pragma unroll
            for (int j = 0; j < 4; ++j)
#pragma unroll
                for (int r = 0; r < 4; ++r) {
                    size_t off = (size_t)(m0 + wm + i * 16 + quad * 4 + r) * N + n0 + wn + j * 16 + fr;
                    ((short*)Cout)[off] = (short)bf16_rtne_bits(acc[i][j][r] * sc);
                }
    } else {
#pragma unroll
        for (int i = 0; i < MI; ++i)
#pragma unroll
            for (int j = 0; j < 4; ++j)
#pragma unroll
                for (int r = 0; r < 4; ++r) {
                    size_t off = (size_t)(m0 + wm + i * 16 + quad * 4 + r) * N + n0 + wn + j * 16 + fr;
                    ((float*)Cout)[off] = acc[i][j][r];
                }
    }
}

// LDS-staged attention, 256-t tile, double-buffered K/V LDS, one barrier per
// s-iter. P in registers via permlane redistribution. (Proven R3 body.)
//
// R12/R13: NCHUNK=4 with launch_bounds(256,2) — the CORRECTED occupancy test
// (resubmitted after an infra-only bench failure; source unchanged).
// R5's NCHUNK=4 failed only because launch_bounds(256,4) forced a 64-VGPR
// cap onto the 116-VGPR body (spill: WRITE 1.4GB). Resource math without the
// cap: VGPR 116 <= 128 permits 16 waves/CU; LDS 4x37888 = 151.5KB <= 160KB
// -> 4 blocks/CU is feasible. Current 18% occupancy is GRID-limited
// (512 blocks = exactly 2/CU). 1024 blocks = 4/CU doubles the independent
// wave streams per SIMD; per-unit-work LDS traffic unchanged (TB=256 keeps
// fragment reuse). Pipe model: serialized-sum wall 81us -> overlapped floor
// ~37us (MFMA) / ~32us (LDS pipe).
// part chunks live in regions dead during attn: {0, 8M, 48M, 56M}.
__global__ __launch_bounds__(256, 2) void attn_mfma(
    const short* __restrict__ qkvb, const short* __restrict__ vtb,
    short* __restrict__ wsb)
{
    __shared__ __align__(16) short Ks[2][64][72];    // [buf][s][d]
    __shared__ __align__(16) short Vt[2][64][72];    // [buf][d][s]
    __shared__ float red[256];

    const int tid = threadIdx.x;
    const int t0 = blockIdx.x * TB;
    const int h  = blockIdx.y;
    const int chunk = blockIdx.z;
    const int srow = tid >> 2;          // 0..63 staging row
    const int sch  = (tid & 3) * 16;    // 0,16,32,48 staging col chunk
    const int wv   = tid >> 6;
    const int lane = tid & 63;
    const int fr   = lane & 15;
    const int quad = lane >> 4;
    const int tb   = wv * 64;           // wave's t-strip base within the tile

    // ---- Q fragments (B-operand) direct from global: 4 strips x 2 k-halves
    short8 qf[4][2];
#pragma unroll
    for (int jt = 0; jt < 4; ++jt) {
        const short* qsrc = qkvb + (size_t)(t0 + tb + jt * 16 + fr) * QKV_COLS + h * HDIM + quad * 8;
        qf[jt][0] = *(const short8*)qsrc;
        qf[jt][1] = *(const short8*)(qsrc + 32);
    }

    short8 ones;
#pragma unroll
    for (int m = 0; m < 8; ++m) ones[m] = (short)0x3F80;   // bf16 1.0

    f32x4 oaccT[4][4] = {};   // [jd][jt], O^T[d][t]
    f32x4 racc[4] = {};       // P column sums per jt (quad-duplicated)

    const int s_begin = chunk * SCHUNK;
    const short* kbase = qkvb + DIM + h * HDIM + sch;
    const short* vbase = vtb + (size_t)(h * HDIM + srow) * TLEN + sch;

    uint4 kA, kB, vA, vB;
    // tile 0 -> regs -> buf0
    {
        const short* ks = kbase + (size_t)(s_begin + srow) * QKV_COLS;
        kA = *(const uint4*)ks;  kB = *(const uint4*)(ks + 8);
        const short* vs = vbase + s_begin;
        vA = *(const uint4*)vs;  vB = *(const uint4*)(vs + 8);
    }
    *(uint4*)&Ks[0][srow][sch]     = kA;
    *(uint4*)&Ks[0][srow][sch + 8] = kB;
    *(uint4*)&Vt[0][srow][sch]     = vA;
    *(uint4*)&Vt[0][srow][sch + 8] = vB;
    // tile 1 -> regs (written to buf1 inside iter 0)
    {
        const short* ks = kbase + (size_t)(s_begin + 64 + srow) * QKV_COLS;
        kA = *(const uint4*)ks;  kB = *(const uint4*)(ks + 8);
        const short* vs = vbase + s_begin + 64;
        vA = *(const uint4*)vs;  vB = *(const uint4*)(vs + 8);
    }
    __syncthreads();

    auto step = [&](short (*KsC)[72], short (*VtC)[72],
                    short (*KsN)[72], short (*VtN)[72], int it) {
        // write next tile into the other buffer (overlaps this tile's compute)
        if (it + 1 < NIT) {
            *(uint4*)&KsN[srow][sch]     = kA;
            *(uint4*)&KsN[srow][sch + 8] = kB;
            *(uint4*)&VtN[srow][sch]     = vA;
            *(uint4*)&VtN[srow][sch + 8] = vB;
        }
        // issue tile+2 global loads; latency hides under compute
        if (it + 2 < NIT) {
            const int s0n = s_begin + (it + 2) * 64;
            const short* ks = kbase + (size_t)(s0n + srow) * QKV_COLS;
            kA = *(const uint4*)ks;  kB = *(const uint4*)(ks + 8);
            const short* vs = vbase + s0n;
            vA = *(const uint4*)vs;  vB = *(const uint4*)(vs + 8);
        }

        // K and V fragments for this s-tile (reused across all 4 t-strips)
        short8 kf[4][2], vf[4][2];
#pragma unroll
        for (int i = 0; i < 4; ++i) {
            kf[i][0] = *(const short8*)&KsC[i * 16 + fr][quad * 8];
            kf[i][1] = *(const short8*)&KsC[i * 16 + fr][32 + quad * 8];
            vf[i][0] = *(const short8*)&VtC[i * 16 + fr][quad * 8];
            vf[i][1] = *(const short8*)&VtC[i * 16 + fr][32 + quad * 8];
        }

#pragma unroll
        for (int jt = 0; jt < 4; ++jt) {
            // S^T = K.Q^T: lane holds s = i*16+quad*4+r, t = tb+jt*16+fr
            unsigned w0[4], w1[4];   // w[i][p]: bf16 pair for s = i*16+quad*4+2p,+1
#pragma unroll
            for (int i = 0; i < 4; ++i) {
                f32x4 acc = {};
                acc = __builtin_amdgcn_mfma_f32_16x16x32_bf16(kf[i][0], qf[jt][0], acc, 0, 0, 0);
                acc = __builtin_amdgcn_mfma_f32_16x16x32_bf16(kf[i][1], qf[jt][1], acc, 0, 0, 0);
                unsigned u0 = __float_as_uint(__builtin_amdgcn_exp2f(acc[0]));
                unsigned u1 = __float_as_uint(__builtin_amdgcn_exp2f(acc[1]));
                unsigned u2 = __float_as_uint(__builtin_amdgcn_exp2f(acc[2]));
                unsigned u3 = __float_as_uint(__builtin_amdgcn_exp2f(acc[3]));
                w0[i] = __builtin_amdgcn_perm(u1, u0, 0x07060302);  // trunc-pack
                w1[i] = __builtin_amdgcn_perm(u3, u2, 0x07060302);
            }
            // in-register redistribution to PV B-fragment layout:
            //   after pl32swap(w[2k],w[2k+1]):  a0 = w[q1]@src(0,q0), a1 = w[q1]@src(1,q0)
            //   after pl16swap(a0,a1):          o0 = w[q1]@src(q0,0), o1 = w[q1]@src(q0,1)
            auto A0 = __builtin_amdgcn_permlane32_swap(w0[0], w0[1], false, false);
            auto A2 = __builtin_amdgcn_permlane32_swap(w0[2], w0[3], false, false);
            auto B0 = __builtin_amdgcn_permlane32_swap(w1[0], w1[1], false, false);
            auto B2 = __builtin_amdgcn_permlane32_swap(w1[2], w1[3], false, false);
            auto O0 = __builtin_amdgcn_permlane16_swap(A0[0], A0[1], false, false);
            auto O2 = __builtin_amdgcn_permlane16_swap(A2[0], A2[1], false, false);
            auto P0 = __builtin_amdgcn_permlane16_swap(B0[0], B0[1], false, false);
            auto P2 = __builtin_amdgcn_permlane16_swap(B2[0], B2[1], false, false);
            short8 pb0 = mk8(O0[0], P0[0], O0[1], P0[1]);   // kh=0: s = quad*8+0..7
            short8 pb1 = mk8(O2[0], P2[0], O2[1], P2[1]);   // kh=1: s = 32+quad*8+0..7

            __builtin_amdgcn_s_setprio(1);
            // P column sums via ones-row MFMA (sums the truncated P exactly)
            racc[jt] = __builtin_amdgcn_mfma_f32_16x16x32_bf16(ones, pb0, racc[jt], 0, 0, 0);
            racc[jt] = __builtin_amdgcn_mfma_f32_16x16x32_bf16(ones, pb1, racc[jt], 0, 0, 0);

            // O^T += V^T.P
#pragma unroll
            for (int jd = 0; jd < 4; ++jd) {
                oaccT[jd][jt] = __builtin_amdgcn_mfma_f32_16x16x32_bf16(vf[jd][0], pb0, oaccT[jd][jt], 0, 0, 0);
                oaccT[jd][jt] = __builtin_amdgcn_mfma_f32_16x16x32_bf16(vf[jd][1], pb1, oaccT[jd][jt], 0, 0, 0);
            }
            __builtin_amdgcn_s_setprio(0);
        }
        __syncthreads();   // my writes drained for next iter's readers; my
                           // reads of KsC/VtC done for next iter's writers
    };

    for (int it = 0; it < NIT; it += 2) {
        step(Ks[0], Vt[0], Ks[1], Vt[1], it);
        step(Ks[1], Vt[1], Ks[0], Vt[0], it + 1);
    }

    // ---- epilogue: O^T[d][t] -> part[chunk][t][h*64+d], bf16, b64 stores ----
    // chunk bases (in shorts) over regions dead during attn:
    //   c0 @ ws+0 (xb), c1 @ ws+8M (wib/wob), c2 @ ws+48M, c3 @ ws+56M
    size_t choff = (chunk == 0) ? 0
                 : (chunk == 1) ? ((size_t)(8u << 20) >> 1)
                 : (chunk == 2) ? ((size_t)(48u << 20) >> 1)
                 :                ((size_t)(56u << 20) >> 1);
    short* pc = wsb + choff;
#pragma unroll
    for (int jt = 0; jt < 4; ++jt)
#pragma unroll
        for (int jd = 0; jd < 4; ++jd) {
            unsigned u0 = bf16_rtne_bits(oaccT[jd][jt][0]);
            unsigned u1 = bf16_rtne_bits(oaccT[jd][jt][1]);
            unsigned u2 = bf16_rtne_bits(oaccT[jd][jt][2]);
            unsigned u3 = bf16_rtne_bits(oaccT[jd][jt][3]);
            uint2 pk;
            pk.x = u0 | (u1 << 16);
            pk.y = u2 | (u3 << 16);
            *(uint2*)(pc + (size_t)(t0 + tb + jt * 16 + fr) * DIM + h * HDIM + jd * 16 + quad * 4) = pk;
        }

    // ---- block-reduce L, one atomic per block (racc quad-duplicated /4) ----
    red[tid] = (racc[0][0] + racc[1][0] + racc[2][0] + racc[3][0]) * 0.25f;
    __syncthreads();
    for (int off = 128; off > 0; off >>= 1) {
        if (tid < off) red[tid] += red[tid + off];
        __syncthreads();
    }
    if (tid == 0) atomicAdd(&g_Lsum[h], red[0]);
}

extern "C" void kernel_launch(void* const* d_in, const int* in_sizes, int n_in,
                              void* d_out, int out_size, void* d_ws, size_t ws_size,
                              hipStream_t stream)
{
    const float* x     = (const float*)d_in[0];   // [4096, 1024]
    const float* W_in  = (const float*)d_in[1];   // [3072, 1024]
    const float* W_out = (const float*)d_in[2];   // [1024, 1024]
    float* out = (float*)d_out;                   // [4096, 1024] fp32

    char* ws = (char*)d_ws;
    short* xb    = (short*)(ws);                   //  8 MiB @ 0   (later: part c0 / attnb)
    short* wib   = (short*)(ws + (8u << 20));      //  6 MiB @ 8M  (later: part c1)
    short* wob   = (short*)(ws + (14u << 20));     //  2 MiB @ 14M (written after combine4)
    short* qkvb  = (short*)(ws + (16u << 20));     // 24 MiB @ 16M (V region unused)
    short* vtb   = (short*)(ws + (40u << 20));     //  8 MiB @ 40M (V^T [d_global][s])
    short* partc2= (short*)(ws + (48u << 20));     //  8 MiB @ 48M
    short* partc3= (short*)(ws + (56u << 20));     //  8 MiB @ 56M
    short* attnb = xb;                             // combine4 dst (in-place over c0)
    // total: exactly 64 MiB. During attn, regions {0-8M, 8-16M, 48-64M} hold
    // the 4 part chunks (xb/wib dead after gemm<true>; wob written AFTER
    // combine4 consumes c1 — R5-proven flow).

    // fused conversions: x -> xb, W_in -> wib (one launch)
    conv_in<<<(TLEN * DIM / 4 + QKV_COLS * DIM / 4 + 255) / 256, 256, 0, stream>>>(
        x, W_in, xb, wib);

    // qkv = x @ W_in^T  (bf16 MFMA; Q cols x0.125*log2e; V cols -> vtb
    // transposed; also zeroes g_Lsum before attn; XCD-swizzled grid)
    gemm_bt<true, 128><<<dim3(TLEN / 128, QKV_COLS / 128), 256, 0, stream>>>(
        xb, wib, qkvb, vtb, TLEN, QKV_COLS, DIM);

    // 1024 blocks = 4 blocks/CU (VGPR 116 <= 128, LDS 4x37.9KB <= 160KB)
    attn_mfma<<<dim3(TLEN / TB, NHEAD, NCHUNK), 256, 0, stream>>>(
        qkvb, vtb, (short*)ws);

    // combine BEFORE conv_wout (wob region overlays part c1)
    combine4<<<(TLEN * DIM / 4 + 255) / 256, 256, 0, stream>>>(
        xb, wib, partc2, partc3, attnb, TLEN * DIM / 4);

    conv_wout<<<DIM * DIM / 4 / 256, 256, 0, stream>>>(W_out, wob);

    // out = attn' @ (W_out/L)^T  (bf16 MFMA, fp32 out; BM=64, XCD-swizzled)
    gemm_bt<false, 64><<<dim3(TLEN / 64, DIM / 128), 256, 0, stream>>>(
        attnb, wob, out, nullptr, TLEN, DIM, DIM);
}

// Round 14
// 212.363 us; speedup vs baseline: 1.0564x; 1.0564x over previous
//
#include <hip/hip_runtime.h>

#define TLEN 4096
#define DIM 1024
#define NHEAD 16
#define HDIM 64
#define QKV_COLS (3 * DIM)
// 0.125 * log2(e): attention scores computed in exp2 domain (v_exp_f32 is 2^x)
#define QSCALE 0.1803368801111244f
#define NCHUNK 2
#define SCHUNK (TLEN / NCHUNK)
#define TB 256        // t rows per attn block (wave owns 64 t = 4 strips of 16)
#define NIT (SCHUNK / 64)

typedef __attribute__((ext_vector_type(8))) short short8;   // 8 bf16 = 4 VGPR (MFMA A/B frag)
typedef __attribute__((ext_vector_type(4))) float f32x4;    // MFMA C/D frag

struct alignas(8) s4 { short v[4]; };

__device__ float g_Lsum[NHEAD];

__device__ __forceinline__ unsigned bf16_rtne_bits(float x) {
    unsigned u = __float_as_uint(x);
    return (u + 0x7fffu + ((u >> 16) & 1u)) >> 16;
}

// async global->LDS 16B copy (global_load_lds_dwordx4). LDS dest must be
// wave-uniform base + lane*16 at the callsite (our staging layouts are).
__device__ __forceinline__ void cp16(const short* g, short* l) {
    __builtin_amdgcn_global_load_lds(
        (const __attribute__((address_space(1))) unsigned int*)g,
        (__attribute__((address_space(3))) unsigned int*)l,
        16, 0, 0);
}

__device__ __forceinline__ short8 mk8(unsigned a, unsigned b, unsigned c, unsigned d) {
    union { unsigned u[4]; short8 s; } t;
    t.u[0] = a; t.u[1] = b; t.u[2] = c; t.u[3] = d;
    return t.s;
}

// Fused fp32->bf16 conversion of x (4M elems) and W_in (3M elems); one launch.
__global__ __launch_bounds__(256) void conv_in(
    const float* __restrict__ x, const float* __restrict__ W_in,
    short* __restrict__ xb, short* __restrict__ wib)
{
    const int XN4 = TLEN * DIM / 4;        // 1048576
    const int WN4 = QKV_COLS * DIM / 4;    // 786432
    int i = blockIdx.x * 256 + threadIdx.x;
    const float* src; short* dst; int j;
    if (i < XN4)            { src = x;    dst = xb;  j = i; }
    else if (i < XN4 + WN4) { src = W_in; dst = wib; j = i - XN4; }
    else return;
    float4 v = ((const float4*)src)[j];
    s4 o;
    o.v[0] = (short)bf16_rtne_bits(v.x);
    o.v[1] = (short)bf16_rtne_bits(v.y);
    o.v[2] = (short)bf16_rtne_bits(v.z);
    o.v[3] = (short)bf16_rtne_bits(v.w);
    ((s4*)dst)[j] = o;
}

// Fused post-attn pass (one launch):
//  blocks [0,1024):   W_out -> bf16 wob with per-head 1/L folded in
//  blocks [1024,5120): attnb = bf16(part0 + part1)
// Both paths identical math to the previous separate kernels.
__global__ __launch_bounds__(256) void post_attn(
    const float* __restrict__ W_out, short* __restrict__ wob,
    const short* __restrict__ p0, const short* __restrict__ p1,
    short* __restrict__ dst)
{
    const int WB = DIM * DIM / 4 / 256;    // 1024 blocks for the wout path
    if (blockIdx.x < WB) {
        int i = blockIdx.x * 256 + threadIdx.x;   // over 1024*1024/4
        float s = 1.0f / g_Lsum[(i & 255) >> 4];  // k = (i&255)*4; head = k>>6
        float4 v = ((const float4*)W_out)[i];
        s4 o;
        o.v[0] = (short)bf16_rtne_bits(v.x * s);
        o.v[1] = (short)bf16_rtne_bits(v.y * s);
        o.v[2] = (short)bf16_rtne_bits(v.z * s);
        o.v[3] = (short)bf16_rtne_bits(v.w * s);
        ((s4*)wob)[i] = o;
    } else {
        int i = (blockIdx.x - WB) * 256 + threadIdx.x;
        if (i < TLEN * DIM / 4) {
            s4 a = ((const s4*)p0)[i];
            s4 b = ((const s4*)p1)[i];
            s4 o;
#pragma unroll
            for (int m = 0; m < 4; ++m) {
                float fa = __uint_as_float(((unsigned)(unsigned short)a.v[m]) << 16);
                float fb = __uint_as_float(((unsigned)(unsigned short)b.v[m]) << 16);
                o.v[m] = (short)bf16_rtne_bits(fa + fb);
            }
            ((s4*)dst)[i] = o;
        }
    }
}

// C = A @ B^T, bf16 MFMA. BMx128 tile (BM=128 or 64), 4 waves, BK=32.
// Staging via async global_load_lds width=16.
// QKV_MODE: bf16 out; Q cols (n<DIM) scaled by QSCALE; V cols (n>=2*DIM)
//   written TRANSPOSED to Vout[d_global][t] as packed uint2. Also zeroes
//   g_Lsum from one designated block (attn runs strictly after in stream).
// else: fp32 out to Cout.
template <bool QKV_MODE, int BM>
__global__ __launch_bounds__(256) void gemm_bt(
    const short* __restrict__ A, const short* __restrict__ B,
    void* __restrict__ Cout, short* __restrict__ Vout, int M, int N, int K)
{
    constexpr int MI = BM / 32;   // i-strips per wave (wave covers BM/2 rows)
    __shared__ __align__(16) short As[BM][32];
    __shared__ __align__(16) short Bs[128][32];
    const int tid  = threadIdx.x;
    const int wv   = tid >> 6, lane = tid & 63;
    const int fr   = lane & 15, quad = lane >> 4;
    const int wm   = (wv >> 1) * (BM / 2), wn = (wv & 1) * 64;
    const int m0 = blockIdx.x * BM, n0 = blockIdx.y * 128;

    if (QKV_MODE && blockIdx.x == 0 && blockIdx.y == 0 && tid < NHEAD)
        g_Lsum[tid] = 0.0f;

    f32x4 acc[MI][4] = {};

    for (int k0 = 0; k0 < K; k0 += 32) {
        __syncthreads();
#pragma unroll
        for (int c = tid; c < 512; c += 256) {
            int row = c >> 2, col = (c & 3) * 8;
            if (BM == 128 || c < BM * 4)
                cp16(A + (size_t)(m0 + row) * K + k0 + col, &As[row][col]);
            cp16(B + (size_t)(n0 + row) * K + k0 + col, &Bs[row][col]);
        }
        __syncthreads();   // drains vmcnt (async LDS stores) before reads

        short8 af[MI], bfr[4];
#pragma unroll
        for (int i = 0; i < MI; ++i)
            af[i]  = *(const short8*)&As[wm + i * 16 + fr][quad * 8];
#pragma unroll
        for (int j = 0; j < 4; ++j)
            bfr[j] = *(const short8*)&Bs[wn + j * 16 + fr][quad * 8];
#pragma unroll
        for (int i = 0; i < MI; ++i)
#pragma unroll
            for (int j = 0; j < 4; ++j)
                acc[i][j] = __builtin_amdgcn_mfma_f32_16x16x32_bf16(af[i], bfr[j], acc[i][j], 0, 0, 0);
    }

    if (QKV_MODE && n0 >= 2 * DIM) {
        // V tile: write V^T[d_global][t], packed 4 consecutive t per lane
#pragma unroll
        for (int i = 0; i < MI; ++i)
#pragma unroll
            for (int j = 0; j < 4; ++j) {
                int n = n0 - 2 * DIM + wn + j * 16 + fr;        // d_global
                int m = m0 + wm + i * 16 + quad * 4;            // t base
                unsigned u0 = bf16_rtne_bits(acc[i][j][0]);
                unsigned u1 = bf16_rtne_bits(acc[i][j][1]);
                unsigned u2 = bf16_rtne_bits(acc[i][j][2]);
                unsigned u3 = bf16_rtne_bits(acc[i][j][3]);
                uint2 pk;
                pk.x = u0 | (u1 << 16);
                pk.y = u2 | (u3 << 16);
                *(uint2*)(Vout + (size_t)n * TLEN + m) = pk;
            }
    } else if (QKV_MODE) {
        const float sc = (n0 < DIM) ? QSCALE : 1.0f;
#pragma unroll
        for (int i = 0; i < MI; ++i)
#pragma unroll
            for (int j = 0; j < 4; ++j)
#pragma unroll
                for (int r = 0; r < 4; ++r) {
                    size_t off = (size_t)(m0 + wm + i * 16 + quad * 4 + r) * N + n0 + wn + j * 16 + fr;
                    ((short*)Cout)[off] = (short)bf16_rtne_bits(acc[i][j][r] * sc);
                }
    } else {
#pragma unroll
        for (int i = 0; i < MI; ++i)
#pragma unroll
            for (int j = 0; j < 4; ++j)
#pragma unroll
                for (int r = 0; r < 4; ++r) {
                    size_t off = (size_t)(m0 + wm + i * 16 + quad * 4 + r) * N + n0 + wn + j * 16 + fr;
                    ((float*)Cout)[off] = acc[i][j][r];
                }
    }
}

// LDS-staged attention, 256-t tile, double-buffered K/V LDS, one barrier per
// s-iter. P in registers via permlane redistribution. (R3 structure —
// best of 9 structural variants across the session; see ledger in the
// session journal. The anti-phase start is retained from the best-measured
// R8 build: null on attn in isolation, harmless, and part of the exact
// 214.7us configuration being restored.)
__global__ __launch_bounds__(256, 2) void attn_mfma(
    const short* __restrict__ qkvb, const short* __restrict__ vtb,
    short* __restrict__ part)
{
    __shared__ __align__(16) short Ks[2][64][72];    // [buf][s][d]
    __shared__ __align__(16) short Vt[2][64][72];    // [buf][d][s]
    __shared__ float red[256];

    // anti-phase: offset half the blocks by ~half an iteration period
    if ((blockIdx.x + blockIdx.y + blockIdx.z) & 1) {
#pragma unroll
        for (int z = 0; z < 6; ++z) __builtin_amdgcn_s_sleep(8);   // 6*512 cyc
    }

    const int tid = threadIdx.x;
    const int t0 = blockIdx.x * TB;
    const int h  = blockIdx.y;
    const int chunk = blockIdx.z;
    const int srow = tid >> 2;          // 0..63 staging row
    const int sch  = (tid & 3) * 16;    // 0,16,32,48 staging col chunk
    const int wv   = tid >> 6;
    const int lane = tid & 63;
    const int fr   = lane & 15;
    const int quad = lane >> 4;
    const int tb   = wv * 64;           // wave's t-strip base within the tile

    // ---- Q fragments (B-operand) direct from global: 4 strips x 2 k-halves
    short8 qf[4][2];
#pragma unroll
    for (int jt = 0; jt < 4; ++jt) {
        const short* qsrc = qkvb + (size_t)(t0 + tb + jt * 16 + fr) * QKV_COLS + h * HDIM + quad * 8;
        qf[jt][0] = *(const short8*)qsrc;
        qf[jt][1] = *(const short8*)(qsrc + 32);
    }

    short8 ones;
#pragma unroll
    for (int m = 0; m < 8; ++m) ones[m] = (short)0x3F80;   // bf16 1.0

    f32x4 oaccT[4][4] = {};   // [jd][jt], O^T[d][t]
    f32x4 racc[4] = {};       // P column sums per jt (quad-duplicated)

    const int s_begin = chunk * SCHUNK;
    const short* kbase = qkvb + DIM + h * HDIM + sch;
    const short* vbase = vtb + (size_t)(h * HDIM + srow) * TLEN + sch;

    uint4 kA, kB, vA, vB;
    // tile 0 -> regs -> buf0
    {
        const short* ks = kbase + (size_t)(s_begin + srow) * QKV_COLS;
        kA = *(const uint4*)ks;  kB = *(const uint4*)(ks + 8);
        const short* vs = vbase + s_begin;
        vA = *(const uint4*)vs;  vB = *(const uint4*)(vs + 8);
    }
    *(uint4*)&Ks[0][srow][sch]     = kA;
    *(uint4*)&Ks[0][srow][sch + 8] = kB;
    *(uint4*)&Vt[0][srow][sch]     = vA;
    *(uint4*)&Vt[0][srow][sch + 8] = vB;
    // tile 1 -> regs (written to buf1 inside iter 0)
    {
        const short* ks = kbase + (size_t)(s_begin + 64 + srow) * QKV_COLS;
        kA = *(const uint4*)ks;  kB = *(const uint4*)(ks + 8);
        const short* vs = vbase + s_begin + 64;
        vA = *(const uint4*)vs;  vB = *(const uint4*)(vs + 8);
    }
    __syncthreads();

    auto step = [&](short (*KsC)[72], short (*VtC)[72],
                    short (*KsN)[72], short (*VtN)[72], int it) {
        // write next tile into the other buffer (overlaps this tile's compute)
        if (it + 1 < NIT) {
            *(uint4*)&KsN[srow][sch]     = kA;
            *(uint4*)&KsN[srow][sch + 8] = kB;
            *(uint4*)&VtN[srow][sch]     = vA;
            *(uint4*)&VtN[srow][sch + 8] = vB;
        }
        // issue tile+2 global loads; latency hides under compute
        if (it + 2 < NIT) {
            const int s0n = s_begin + (it + 2) * 64;
            const short* ks = kbase + (size_t)(s0n + srow) * QKV_COLS;
            kA = *(const uint4*)ks;  kB = *(const uint4*)(ks + 8);
            const short* vs = vbase + s0n;
            vA = *(const uint4*)vs;  vB = *(const uint4*)(vs + 8);
        }

        // K and V fragments for this s-tile (reused across all 4 t-strips)
        short8 kf[4][2], vf[4][2];
#pragma unroll
        for (int i = 0; i < 4; ++i) {
            kf[i][0] = *(const short8*)&KsC[i * 16 + fr][quad * 8];
            kf[i][1] = *(const short8*)&KsC[i * 16 + fr][32 + quad * 8];
            vf[i][0] = *(const short8*)&VtC[i * 16 + fr][quad * 8];
            vf[i][1] = *(const short8*)&VtC[i * 16 + fr][32 + quad * 8];
        }

#pragma unroll
        for (int jt = 0; jt < 4; ++jt) {
            // S^T = K.Q^T: lane holds s = i*16+quad*4+r, t = tb+jt*16+fr
            unsigned w0[4], w1[4];   // w[i][p]: bf16 pair for s = i*16+quad*4+2p,+1
#pragma unroll
            for (int i = 0; i < 4; ++i) {
                f32x4 acc = {};
                acc = __builtin_amdgcn_mfma_f32_16x16x32_bf16(kf[i][0], qf[jt][0], acc, 0, 0, 0);
                acc = __builtin_amdgcn_mfma_f32_16x16x32_bf16(kf[i][1], qf[jt][1], acc, 0, 0, 0);
                unsigned u0 = __float_as_uint(__builtin_amdgcn_exp2f(acc[0]));
                unsigned u1 = __float_as_uint(__builtin_amdgcn_exp2f(acc[1]));
                unsigned u2 = __float_as_uint(__builtin_amdgcn_exp2f(acc[2]));
                unsigned u3 = __float_as_uint(__builtin_amdgcn_exp2f(acc[3]));
                w0[i] = __builtin_amdgcn_perm(u1, u0, 0x07060302);  // trunc-pack
                w1[i] = __builtin_amdgcn_perm(u3, u2, 0x07060302);
            }
            // in-register redistribution to PV B-fragment layout:
            //   after pl32swap(w[2k],w[2k+1]):  a0 = w[q1]@src(0,q0), a1 = w[q1]@src(1,q0)
            //   after pl16swap(a0,a1):          o0 = w[q1]@src(q0,0), o1 = w[q1]@src(q0,1)
            auto A0 = __builtin_amdgcn_permlane32_swap(w0[0], w0[1], false, false);
            auto A2 = __builtin_amdgcn_permlane32_swap(w0[2], w0[3], false, false);
            auto B0 = __builtin_amdgcn_permlane32_swap(w1[0], w1[1], false, false);
            auto B2 = __builtin_amdgcn_permlane32_swap(w1[2], w1[3], false, false);
            auto O0 = __builtin_amdgcn_permlane16_swap(A0[0], A0[1], false, false);
            auto O2 = __builtin_amdgcn_permlane16_swap(A2[0], A2[1], false, false);
            auto P0 = __builtin_amdgcn_permlane16_swap(B0[0], B0[1], false, false);
            auto P2 = __builtin_amdgcn_permlane16_swap(B2[0], B2[1], false, false);
            short8 pb0 = mk8(O0[0], P0[0], O0[1], P0[1]);   // kh=0: s = quad*8+0..7
            short8 pb1 = mk8(O2[0], P2[0], O2[1], P2[1]);   // kh=1: s = 32+quad*8+0..7

            __builtin_amdgcn_s_setprio(1);
            // P column sums via ones-row MFMA (sums the truncated P exactly)
            racc[jt] = __builtin_amdgcn_mfma_f32_16x16x32_bf16(ones, pb0, racc[jt], 0, 0, 0);
            racc[jt] = __builtin_amdgcn_mfma_f32_16x16x32_bf16(ones, pb1, racc[jt], 0, 0, 0);

            // O^T += V^T.P
#pragma unroll
            for (int jd = 0; jd < 4; ++jd) {
                oaccT[jd][jt] = __builtin_amdgcn_mfma_f32_16x16x32_bf16(vf[jd][0], pb0, oaccT[jd][jt], 0, 0, 0);
                oaccT[jd][jt] = __builtin_amdgcn_mfma_f32_16x16x32_bf16(vf[jd][1], pb1, oaccT[jd][jt], 0, 0, 0);
            }
            __builtin_amdgcn_s_setprio(0);
        }
        __syncthreads();   // my writes drained for next iter's readers; my
                           // reads of KsC/VtC done for next iter's writers
    };

    for (int it = 0; it < NIT; it += 2) {
        step(Ks[0], Vt[0], Ks[1], Vt[1], it);
        step(Ks[1], Vt[1], Ks[0], Vt[0], it + 1);
    }

    // ---- epilogue: O^T[d][t] -> part[chunk][t][h*64+d], bf16, b64 stores ----
    short* pc = part + (size_t)chunk * TLEN * DIM;
#pragma unroll
    for (int jt = 0; jt < 4; ++jt)
#pragma unroll
        for (int jd = 0; jd < 4; ++jd) {
            unsigned u0 = bf16_rtne_bits(oaccT[jd][jt][0]);
            unsigned u1 = bf16_rtne_bits(oaccT[jd][jt][1]);
            unsigned u2 = bf16_rtne_bits(oaccT[jd][jt][2]);
            unsigned u3 = bf16_rtne_bits(oaccT[jd][jt][3]);
            uint2 pk;
            pk.x = u0 | (u1 << 16);
            pk.y = u2 | (u3 << 16);
            *(uint2*)(pc + (size_t)(t0 + tb + jt * 16 + fr) * DIM + h * HDIM + jd * 16 + quad * 4) = pk;
        }

    // ---- block-reduce L, one atomic per block (racc quad-duplicated /4) ----
    red[tid] = (racc[0][0] + racc[1][0] + racc[2][0] + racc[3][0]) * 0.25f;
    __syncthreads();
    for (int off = 128; off > 0; off >>= 1) {
        if (tid < off) red[tid] += red[tid + off];
        __syncthreads();
    }
    if (tid == 0) atomicAdd(&g_Lsum[h], red[0]);
}

extern "C" void kernel_launch(void* const* d_in, const int* in_sizes, int n_in,
                              void* d_out, int out_size, void* d_ws, size_t ws_size,
                              hipStream_t stream)
{
    const float* x     = (const float*)d_in[0];   // [4096, 1024]
    const float* W_in  = (const float*)d_in[1];   // [3072, 1024]
    const float* W_out = (const float*)d_in[2];   // [1024, 1024]
    float* out = (float*)d_out;                   // [4096, 1024] fp32

    char* ws = (char*)d_ws;
    short* xb    = (short*)(ws);                   //  8 MiB @ 0   (later: attnb)
    short* wib   = (short*)(ws + (8u << 20));      //  6 MiB @ 8M
    short* wob   = (short*)(ws + (14u << 20));     //  2 MiB @ 14M
    short* qkvb  = (short*)(ws + (16u << 20));     // 24 MiB @ 16M (V region unused)
    short* vtb   = (short*)(ws + (40u << 20));     //  8 MiB @ 40M (V^T [d_global][s])
    short* part  = (short*)(ws + (48u << 20));     // 16 MiB @ 48M (2 chunks x 8 MiB)
    short* attnb = xb;                             // reuse dead xb region
    // total: exactly 64 MiB (proven layout)

    // fused conversions: x -> xb, W_in -> wib (one launch)
    conv_in<<<(TLEN * DIM / 4 + QKV_COLS * DIM / 4 + 255) / 256, 256, 0, stream>>>(
        x, W_in, xb, wib);

    // qkv = x @ W_in^T  (bf16 MFMA; Q cols x0.125*log2e; V cols -> vtb
    // transposed; also zeroes g_Lsum before attn)
    gemm_bt<true, 128><<<dim3(TLEN / 128, QKV_COLS / 128), 256, 0, stream>>>(
        xb, wib, qkvb, vtb, TLEN, QKV_COLS, DIM);

    attn_mfma<<<dim3(TLEN / TB, NHEAD, NCHUNK), 256, 0, stream>>>(qkvb, vtb, part);

    // fused: conv_wout (W_out/L -> wob) + combine (part0+part1 -> attnb)
    post_attn<<<DIM * DIM / 4 / 256 + (TLEN * DIM / 4 + 255) / 256, 256, 0, stream>>>(
        W_out, wob, part, part + (size_t)TLEN * DIM, attnb);

    // out = attn' @ (W_out/L)^T  (bf16 MFMA, fp32 out; BM=64 -> 512 blocks)
    gemm_bt<false, 64><<<dim3(TLEN / 64, DIM / 128), 256, 0, stream>>>(
        attnb, wob, out, nullptr, TLEN, DIM, DIM);
}